// Round 4
// baseline (233.214 us; speedup 1.0000x reference)
//
#include <hip/hip_runtime.h>

// YOLOv1 loss: batch x 7 x 7 x 30 fp32 (y_trues, y_preds) -> scalar.
// R1 (strided dwordx2/thread): 77us. R3 (strided dwordx4, 2 cells/thread):
// 80us -- SAME despite half the vmem instrs => not instruction-bound.
// Theory: 16B-granule gathers at 120-240B stride waste 7/8 of every 128B
// line through L1 (thrashed) => ~8x internal amplification => ~78us wall.
// R2 (LDS staging via VGPR round-trip + 3 barriers): 96us -- coalescing won
// but overheads lost more.
// R4: async coalesced staging via __builtin_amdgcn_global_load_lds(16B):
// no VGPR round-trip, 30 block-wide load instrs, one barrier, compute from
// LDS. 128-cell tiles, 30KB LDS -> 5 blocks/CU for inter-block overlap.

#define SS 49
#define DD 30
#define TPB 128                        // threads = cells per tile
#define TILE_F (TPB * DD)              // 3840 floats per tensor
#define TILE_F4 (TILE_F / 4)           // 960 float4 per tensor
#define NCHUNK 30                      // 2 tensors * 15 chunks of 1024B

__device__ __forceinline__ void async_copy16(const float* g, float* l) {
    __builtin_amdgcn_global_load_lds(
        (const __attribute__((address_space(1))) void*)g,
        (__attribute__((address_space(3))) void*)l, 16, 0, 0);
}

__global__ __launch_bounds__(TPB)
void yolo_loss_kernel(const float* __restrict__ yt_g,
                      const float* __restrict__ yp_g,
                      float* __restrict__ out,
                      float inv_batch) {
    const float LAMBDA_COORD = 5.0f;
    const float LAMBDA_NOOBJ = 0.5f;
    const float EPS = 1e-6f;

    // [0 .. 3839] = yt tile, [3840 .. 7679] = yp tile (contiguous, unpadded:
    // global_load_lds writes wave-uniform-base + lane*16, no padding allowed)
    __shared__ float smem[2 * TILE_F];
    __shared__ float wsum[TPB / 64];

    const int tid = threadIdx.x;
    const int lane = tid & 63;
    const int wave = tid >> 6;                    // 0 or 1
    const size_t tile_base = (size_t)blockIdx.x * TILE_F;  // in floats

    // 30 chunks of 1024B (64 lanes x 16B); wave w issues chunks w, w+2, ...
    // chunk j<15 -> yt, j>=15 -> yp. LDS dst = j*1024 + lane*16 (uniform base).
    for (int j = wave; j < NCHUNK; j += 2) {
        const float* g = (j < 15)
            ? yt_g + tile_base + (size_t)j * 256 + lane * 4
            : yp_g + tile_base + (size_t)(j - 15) * 256 + lane * 4;
        async_copy16(g, &smem[j * 256 + lane * 4]);
    }
    __builtin_amdgcn_s_waitcnt(0);   // drain vmcnt (and lgkm) before barrier
    __syncthreads();

    // ---- per-cell loss from LDS (row = 30 floats @ 8B alignment) ----
    const float* yt = &smem[tid * DD];
    const float* yp = &smem[TILE_F + tid * DD];

    float t[DD], p[DD];
#pragma unroll
    for (int i = 0; i < DD / 2; ++i) {
        float2 a = reinterpret_cast<const float2*>(yt)[i];
        t[2 * i] = a.x; t[2 * i + 1] = a.y;
        float2 b = reinterpret_cast<const float2*>(yp)[i];
        p[2 * i] = b.x; p[2 * i + 1] = b.y;
    }

    float obj = (t[4] == 1.0f) ? 1.0f : 0.0f;
    float noobj = 1.0f - obj;

    float tx1 = t[0] - t[2] * 0.5f, ty1 = t[1] - t[3] * 0.5f;
    float tx2 = t[0] + t[2] * 0.5f, ty2 = t[1] + t[3] * 0.5f;
    float ta = fabsf((tx2 - tx1) * (ty2 - ty1));

    float ax1 = p[0] - p[2] * 0.5f, ay1 = p[1] - p[3] * 0.5f;
    float ax2 = p[0] + p[2] * 0.5f, ay2 = p[1] + p[3] * 0.5f;
    float iw1 = fmaxf(fminf(tx2, ax2) - fmaxf(tx1, ax1), 0.0f);
    float ih1 = fmaxf(fminf(ty2, ay2) - fmaxf(ty1, ay1), 0.0f);
    float inter1 = iw1 * ih1;
    float aa = fabsf((ax2 - ax1) * (ay2 - ay1));
    float iou1 = inter1 / (ta + aa - inter1 + EPS);

    float bx1 = p[5] - p[7] * 0.5f, by1 = p[6] - p[8] * 0.5f;
    float bx2 = p[5] + p[7] * 0.5f, by2 = p[6] + p[8] * 0.5f;
    float iw2 = fmaxf(fminf(tx2, bx2) - fmaxf(tx1, bx1), 0.0f);
    float ih2 = fmaxf(fminf(ty2, by2) - fmaxf(ty1, by1), 0.0f);
    float inter2 = iw2 * ih2;
    float ba = fabsf((bx2 - bx1) * (by2 - by1));
    float iou2 = inter2 / (ta + ba - inter2 + EPS);

    bool best1 = iou1 > iou2;
    float bh0 = best1 ? p[0] : p[5];
    float bh1 = best1 ? p[1] : p[6];
    float bh2 = best1 ? p[2] : p[7];
    float bh3 = best1 ? p[3] : p[8];
    float conf_hat       = best1 ? p[4] : p[9];
    float other_conf_hat = best1 ? p[9] : p[4];

    float dx = t[0] - bh0, dy = t[1] - bh1;
    float xy = dx * dx + dy * dy;

    float sw = sqrtf(t[2]) - sqrtf(fabsf(bh2 + EPS));
    float sh = sqrtf(t[3]) - sqrtf(fabsf(bh3 + EPS));
    float wh = sw * sw + sh * sh;

    float dc = t[4] - conf_hat;
    float obj_conf = dc * dc;

    float noobj_in_obj = LAMBDA_NOOBJ * other_conf_hat * other_conf_hat;

    float d4 = t[4] - p[4];
    float d9 = t[4] - p[9];
    float noobj_cells = LAMBDA_NOOBJ * (d4 * d4 + d9 * d9);

    float cls = 0.0f;
#pragma unroll
    for (int k = 10; k < DD; ++k) {
        float d = t[k] - p[k];
        cls += d * d;
    }

    float acc = obj * (LAMBDA_COORD * (xy + wh) + obj_conf + noobj_in_obj + cls)
              + noobj * noobj_cells;

    // wave reduce (64) -> cross-wave -> one atomic per block
#pragma unroll
    for (int off = 32; off > 0; off >>= 1)
        acc += __shfl_down(acc, off, 64);
    if (lane == 0) wsum[wave] = acc;
    __syncthreads();
    if (tid == 0)
        atomicAdd(out, (wsum[0] + wsum[1]) * inv_batch);
}

extern "C" void kernel_launch(void* const* d_in, const int* in_sizes, int n_in,
                              void* d_out, int out_size, void* d_ws, size_t ws_size,
                              hipStream_t stream) {
    const float* yt = (const float*)d_in[0];
    const float* yp = (const float*)d_in[1];
    float* out = (float*)d_out;

    int total = in_sizes[0];          // batch * 49 * 30 floats
    int ncells = total / DD;          // 802816
    int batch = ncells / SS;

    hipMemsetAsync(out, 0, sizeof(float), stream);

    int grid = ncells / TPB;          // 6272 blocks exactly (802816 % 128 == 0)
    yolo_loss_kernel<<<grid, TPB, 0, stream>>>(yt, yp, out, 1.0f / (float)batch);
}